// Round 9
// baseline (681.879 us; speedup 1.0000x reference)
//
#include <hip/hip_runtime.h>
#include <stdint.h>

#define NPRIOR 8400
#define NB 32
#define NCLS 80
#define KTOP 1000
#define CAP 4096   // max candidates ranked (expected ~1500 valid/image)

typedef unsigned long long u64;

// Bit-exact replica of numpy's float32 SIMD exp (Cephes-style, FMA path).
__device__ __forceinline__ float exp_np(float x) {
#pragma clang fp contract(off)
    if (x > 88.72283935546875f) return __builtin_huge_valf();
    if (x < -87.3365478515625f) return 0.0f;
    float q = rintf(x * 1.442695040f);          // v_rndne: round-nearest-even
    float r = fmaf(q, -6.93145752e-1f, x);      // hi split
    r = fmaf(q, -1.42860677e-6f, r);            // lo split
    float p = fmaf(1.9875691500e-4f, r, 1.3981999507e-3f);
    p = fmaf(p, r, 8.3334519073e-3f);
    p = fmaf(p, r, 4.1665795894e-2f);
    p = fmaf(p, r, 1.6666665459e-1f);
    p = fmaf(p, r, 5.0000001201e-1f);
    float r2 = r * r;
    p = fmaf(p, r2, r);
    p = p + 1.0f;
    return ldexpf(p, (int)q);                   // exact 2^q scaling
}
__device__ __forceinline__ float sigm_np(float x) {
#pragma clang fp contract(off)
    float t = exp_np(-x);
    return 1.0f / (1.0f + t);
}

__device__ __forceinline__ void level_of(int n, int& W, int& s, int& loc) {
    if (n < 6400)      { W = 80; s = 8;  loc = n; }
    else if (n < 8000) { W = 40; s = 16; loc = n - 6400; }
    else               { W = 20; s = 32; loc = n - 8000; }
}

__device__ float4 decode32(int b, int n,
                           const float* bb0, const float* bb1, const float* bb2) {
#pragma clang fp contract(off)
    int W, s, loc; level_of(n, W, s, loc);
    const float* bb = (s == 8) ? bb0 : (s == 16) ? bb1 : bb2;
    int hw = W * W;
    int y = loc / W, x = loc - y * W;
    const float* bp = bb + (size_t)b * 4 * hw + y * W + x;
    float fs = (float)s;
    float cx = (float)x * fs, cy = (float)y * fs;
    float xc = bp[0] * fs + cx;
    float yc = bp[hw] * fs + cy;
    float wv = exp_np(bp[2 * hw]) * fs;
    float hv = exp_np(bp[3 * hw]) * fs;
    float wv2 = wv * 0.5f, hv2 = hv * 0.5f;
    float4 r;
    r.x = xc - wv2;
    r.y = yc - hv2;
    r.z = xc + wv2;
    r.w = yc + hv2;
    return r;
}

// ---- Kernel A: score + label + fused compaction to global keys[] ----
__global__ void __launch_bounds__(256) score_k(
    const float* __restrict__ cls0, const float* __restrict__ cls1, const float* __restrict__ cls2,
    const float* __restrict__ ob0,  const float* __restrict__ ob1,  const float* __restrict__ ob2,
    float* __restrict__ sc, int* __restrict__ labels,
    u64* __restrict__ keys, int* __restrict__ cnts)
{
#pragma clang fp contract(off)
    int gid = blockIdx.x * 256 + threadIdx.x;
    if (gid >= NB * NPRIOR) return;
    int b = gid / NPRIOR;
    int n = gid - b * NPRIOR;
    int W, s, loc; level_of(n, W, s, loc);
    const float* cls = (s == 8) ? cls0 : (s == 16) ? cls1 : cls2;
    const float* ob  = (s == 8) ? ob0  : (s == 16) ? ob1  : ob2;
    int hw = W * W;
    int y = loc / W, x = loc - y * W;

    const float* cp = cls + (size_t)b * NCLS * hw + y * W + x;
    float tM = sigm_np(cp[0]);
    int lab = 0;
    for (int c = 1; c < NCLS; ++c) {
        float t = sigm_np(cp[(size_t)c * hw]);
        if (t > tM) { tM = t; lab = c; }
    }
    float sObj = sigm_np(ob[(size_t)b * hw + y * W + x]);
    float score = tM * sObj;
    bool valid = score >= 0.65f;
    sc[gid] = valid ? score : 0.0f;
    labels[gid] = lab;
    if (valid) {
        int pos = atomicAdd(&cnts[b], 1);
        if (pos < CAP)
            keys[(size_t)b * CAP + pos] =
                ((u64)__float_as_uint(score) << 32) | (unsigned)(~(unsigned)n);
    }
}

// ---- Kernel B: parallel all-pairs rank via readlane broadcast (no LDS scan) ----
// rank_i = #{j : key_j > key_i}; keys unique => exact stable-sort permutation.
__global__ void __launch_bounds__(256) rank_k(
    const u64* __restrict__ keys, const int* __restrict__ cnts,
    const float* __restrict__ sc, const int* __restrict__ labels,
    const float* __restrict__ bb0, const float* __restrict__ bb1, const float* __restrict__ bb2,
    float4* __restrict__ sel_box, float* __restrict__ sel_score,
    int* __restrict__ sel_label, int* __restrict__ maxbits, u64* __restrict__ vmask)
{
#pragma clang fp contract(off)
    __shared__ float redbuf[256];
    int b = blockIdx.y, chunk = blockIdx.x, tid = threadIdx.x;
    int cn = min(cnts[b], CAP);
    int base = chunk * 256;
    // housekeeping lives in chunk 0; other blocks fully above cn exit early
    if (chunk != 0 && base >= cn) return;

    const u64* keyimg = keys + (size_t)b * CAP;
    const int* labb = labels + (size_t)b * NPRIOR;
    const float* scb = sc + (size_t)b * NPRIOR;
    int lane = tid & 63;

    int i = base + tid;
    u64 ki = (i < cn) ? keyimg[i] : 0ull;
    int rank = 0;
    for (int jb = 0; jb < cn; jb += 64) {
        int j = jb + lane;
        u64 kv = (j < cn) ? keyimg[j] : 0ull;   // coalesced 512B/wave, L1-hot
        unsigned lo = (unsigned)kv, hi = (unsigned)(kv >> 32);
        int lim = cn - jb;                       // uniform
#pragma unroll
        for (int l = 0; l < 64; ++l) {
            unsigned jlo = __builtin_amdgcn_readlane(lo, l);
            unsigned jhi = __builtin_amdgcn_readlane(hi, l);
            u64 kj = ((u64)jhi << 32) | jlo;
            rank += (l < lim && kj > ki) ? 1 : 0;
        }
    }

    float lmax = 0.0f;
    if (i < cn && rank < KTOP) {
        unsigned n = ~(unsigned)(ki & 0xffffffffull);
        float s = __uint_as_float((unsigned)(ki >> 32));
        float4 bx = decode32(b, (int)n, bb0, bb1, bb2);
        sel_box[(size_t)b * 1024 + rank] = bx;
        sel_score[(size_t)b * 1024 + rank] = s;
        sel_label[(size_t)b * 1024 + rank] = labb[n];
        lmax = fmaxf(fmaxf(fabsf(bx.x), fabsf(bx.y)),
                     fmaxf(fabsf(bx.z), fabsf(bx.w)));
    }

    if (chunk == 0) {
        // rare fill path: fewer than K valid -> lowest-index zero-score priors
        if (cn < KTOP && tid == 0) {
            float lm = 0.0f;
            int r = cn;
            for (int n = 0; n < NPRIOR && r < KTOP; ++n) {
                if (scb[n] == 0.0f) {
                    float4 bx = decode32(b, n, bb0, bb1, bb2);
                    sel_box[(size_t)b * 1024 + r] = bx;
                    sel_score[(size_t)b * 1024 + r] = 0.0f;
                    sel_label[(size_t)b * 1024 + r] = labb[n];
                    lm = fmaxf(lm, fmaxf(fmaxf(fabsf(bx.x), fabsf(bx.y)),
                                         fmaxf(fabsf(bx.z), fabsf(bx.w))));
                    ++r;
                }
            }
            lmax = fmaxf(lmax, lm);
        }
        // padding rows 1000..1023: deterministic zeros (excluded via vmask)
        if (tid < 24) {
            sel_box[(size_t)b * 1024 + 1000 + tid] = make_float4(0.f, 0.f, 0.f, 0.f);
            sel_score[(size_t)b * 1024 + 1000 + tid] = 0.0f;
            sel_label[(size_t)b * 1024 + 1000 + tid] = 0;
        }
        // vmask: first min(cn,KTOP) slots valid (closed form)
        if (tid < 16) {
            int vc = min(cn, KTOP);
            int lo = tid * 64;
            u64 m;
            if (vc >= lo + 64)      m = ~0ull;
            else if (vc <= lo)      m = 0ull;
            else                    m = (1ull << (vc - lo)) - 1ull;
            vmask[b * 16 + tid] = m;
        }
    }

    // block max -> one atomicMax per block (f32-as-int valid: values >= 0)
    redbuf[tid] = lmax;
    __syncthreads();
    for (int off = 128; off > 0; off >>= 1) {
        if (tid < off) redbuf[tid] = fmaxf(redbuf[tid], redbuf[tid + off]);
        __syncthreads();
    }
    if (tid == 0) atomicMax(&maxbits[b], __float_as_int(redbuf[0]));
}

// ---- Kernel C: TRANSPOSED suppression bitmask via row-ballot ----
// Cmask[(b*1024 + col)*16 + rg] : bit j = "row rg*64+j suppresses col" (row<col)
__global__ void __launch_bounds__(256) build_mask_T(
    const float4* __restrict__ sel_box, const int* __restrict__ sel_label,
    const int* __restrict__ maxbits, u64* __restrict__ Cmask)
{
#pragma clang fp contract(off)
    __shared__ float4 ob[1024];
    __shared__ float ar[1024];
    int b = blockIdx.y, gc = blockIdx.x, tid = threadIdx.x;
    float mc = __int_as_float(maxbits[b]) + 1.0f;   // max_coord
    for (int i = tid; i < 1024; i += 256) {
        float4 v = sel_box[(size_t)b * 1024 + i];
        float off = (float)sel_label[(size_t)b * 1024 + i] * mc;
        v.x += off; v.y += off; v.z += off; v.w += off;
        ob[i] = v;
        ar[i] = (v.z - v.x) * (v.w - v.y);   // area of OFFSET box (as ref)
    }
    __syncthreads();
    int wave = tid >> 6, lane = tid & 63;
#pragma unroll
    for (int rgi = 0; rgi < 4; ++rgi) {
        int rg = wave + rgi * 4;          // row group 0..15
        int row = rg * 64 + lane;
        float4 a = ob[row];
        float aa = ar[row];
        for (int cc = 0; cc < 64; ++cc) {
            int col = gc * 64 + cc;
            bool pred = false;
            if (col > row && row < KTOP && col < KTOP) {
                float4 bb = ob[col];      // broadcast (all lanes same addr)
                float tlx = fmaxf(a.x, bb.x), tly = fmaxf(a.y, bb.y);
                float brx = fminf(a.z, bb.z), bry = fminf(a.w, bb.w);
                float w = fmaxf(brx - tlx, 0.0f), h = fmaxf(bry - tly, 0.0f);
                float inter = w * h;
                float uni = (aa + ar[col]) - inter;
                float iou = inter / (uni + 1e-6f);
                pred = iou > 0.65f;
            }
            u64 bits = __ballot(pred);
            if (lane == 0) Cmask[((size_t)b * 1024 + col) * 16 + rg] = bits;
        }
    }
}

// ---- Kernel D: ballot-fixpoint greedy NMS + output ----
__global__ void __launch_bounds__(64) nms_fixpoint_write(
    const u64* __restrict__ Cmask, const u64* __restrict__ vmask,
    const float4* __restrict__ sel_box, const float* __restrict__ sel_score,
    const int* __restrict__ sel_label, float* __restrict__ out)
{
    int b = blockIdx.x, lane = threadIdx.x;
    const u64* Cimg = Cmask + (size_t)b * 1024 * 16;
    u64 Khist[16];
#pragma unroll
    for (int g = 0; g < 16; ++g) {
        int col = g * 64 + lane;
        const u64* ccol = Cimg + (size_t)col * 16;
        bool supp = false;
#pragma unroll
        for (int gp = 0; gp < g; ++gp)
            supp |= (ccol[gp] & Khist[gp]) != 0ull;
        u64 V = vmask[b * 16 + g] & ~__ballot(supp);
        u64 T = ccol[g];
        u64 K = V;
        for (int it = 0; it < 64; ++it) {
            u64 Knew = V & ~__ballot((T & K) != 0ull);
            if (Knew == K) break;        // wave-uniform branch
            K = Knew;
        }
        Khist[g] = K;
    }

    const size_t selo = (size_t)b * 1024;
    float* lab_o = out + (size_t)NB * KTOP * 5;
    float* keep_o = lab_o + (size_t)NB * KTOP;
#pragma unroll
    for (int g = 0; g < 16; ++g) {
        int k = g * 64 + lane;
        if (k >= KTOP) break;
        bool fin = (Khist[g] >> lane) & 1ull;
        float4 bx = sel_box[selo + k];
        float s = sel_score[selo + k];
        int lb = sel_label[selo + k];
        size_t o5 = ((size_t)b * KTOP + k) * 5;
        out[o5 + 0] = fin ? bx.x : 0.0f;
        out[o5 + 1] = fin ? bx.y : 0.0f;
        out[o5 + 2] = fin ? bx.z : 0.0f;
        out[o5 + 3] = fin ? bx.w : 0.0f;
        out[o5 + 4] = fin ? s : 0.0f;
        lab_o[b * KTOP + k] = fin ? (float)lb : -1.0f;
        keep_o[b * KTOP + k] = fin ? 1.0f : 0.0f;
    }
}

extern "C" void kernel_launch(void* const* d_in, const int* in_sizes, int n_in,
                              void* d_out, int out_size, void* d_ws, size_t ws_size,
                              hipStream_t stream) {
    const float* cls0 = (const float*)d_in[0];
    const float* cls1 = (const float*)d_in[1];
    const float* cls2 = (const float*)d_in[2];
    const float* bb0  = (const float*)d_in[3];
    const float* bb1  = (const float*)d_in[4];
    const float* bb2  = (const float*)d_in[5];
    const float* ob0  = (const float*)d_in[6];
    const float* ob1  = (const float*)d_in[7];
    const float* ob2  = (const float*)d_in[8];
    float* out = (float*)d_out;

    char* w = (char*)d_ws;
    size_t used = 0;
    auto alloc = [&](size_t bytes) -> void* {
        void* p = (void*)(w + used);
        used += (bytes + 255) & ~(size_t)255;
        return p;
    };
    float* sc        = (float*)alloc((size_t)NB * NPRIOR * 4);
    int* labels      = (int*)alloc((size_t)NB * NPRIOR * 4);
    u64* keys        = (u64*)alloc((size_t)NB * CAP * 8);
    int* zeroed      = (int*)alloc((size_t)2 * NB * 4);   // cnts | maxbits
    float4* sel_box  = (float4*)alloc((size_t)NB * 1024 * 16);
    float* sel_score = (float*)alloc((size_t)NB * 1024 * 4);
    int* sel_label   = (int*)alloc((size_t)NB * 1024 * 4);
    u64* vmask       = (u64*)alloc((size_t)NB * 16 * 8);
    u64* Cmask       = (u64*)alloc((size_t)NB * 1024 * 16 * 8);

    if (used > ws_size) return;   // OOB-write guard

    int* cnts = zeroed;
    int* maxbits = zeroed + NB;
    hipMemsetAsync(zeroed, 0, 2 * NB * 4, stream);

    int total = NB * NPRIOR;
    score_k<<<(total + 255) / 256, 256, 0, stream>>>(
        cls0, cls1, cls2, ob0, ob1, ob2, sc, labels, keys, cnts);
    rank_k<<<dim3(16, NB), 256, 0, stream>>>(
        keys, cnts, sc, labels, bb0, bb1, bb2,
        sel_box, sel_score, sel_label, maxbits, vmask);
    build_mask_T<<<dim3(16, NB), 256, 0, stream>>>(sel_box, sel_label, maxbits, Cmask);
    nms_fixpoint_write<<<NB, 64, 0, stream>>>(
        Cmask, vmask, sel_box, sel_score, sel_label, out);
}

// Round 10
// 186.989 us; speedup vs baseline: 3.6466x; 3.6466x over previous
//
#include <hip/hip_runtime.h>
#include <stdint.h>

#define NPRIOR 8400
#define NB 32
#define NCLS 80
#define KTOP 1000
#define CAP 8400   // worst-case candidates; never overflows
#define CPAD 16    // ints per counter slot (64B) -> no same-line atomic pileup

typedef unsigned long long u64;

// Bit-exact replica of numpy's float32 SIMD exp (Cephes-style, FMA path).
__device__ __forceinline__ float exp_np(float x) {
#pragma clang fp contract(off)
    if (x > 88.72283935546875f) return __builtin_huge_valf();
    if (x < -87.3365478515625f) return 0.0f;
    float q = rintf(x * 1.442695040f);          // v_rndne: round-nearest-even
    float r = fmaf(q, -6.93145752e-1f, x);      // hi split
    r = fmaf(q, -1.42860677e-6f, r);            // lo split
    float p = fmaf(1.9875691500e-4f, r, 1.3981999507e-3f);
    p = fmaf(p, r, 8.3334519073e-3f);
    p = fmaf(p, r, 4.1665795894e-2f);
    p = fmaf(p, r, 1.6666665459e-1f);
    p = fmaf(p, r, 5.0000001201e-1f);
    float r2 = r * r;
    p = fmaf(p, r2, r);
    p = p + 1.0f;
    return ldexpf(p, (int)q);                   // exact 2^q scaling
}
__device__ __forceinline__ float sigm_np(float x) {
#pragma clang fp contract(off)
    float t = exp_np(-x);
    return 1.0f / (1.0f + t);
}

__device__ __forceinline__ void level_of(int n, int& W, int& s, int& loc) {
    if (n < 6400)      { W = 80; s = 8;  loc = n; }
    else if (n < 8000) { W = 40; s = 16; loc = n - 6400; }
    else               { W = 20; s = 32; loc = n - 8000; }
}

__device__ float4 decode32(int b, int n,
                           const float* bb0, const float* bb1, const float* bb2) {
#pragma clang fp contract(off)
    int W, s, loc; level_of(n, W, s, loc);
    const float* bb = (s == 8) ? bb0 : (s == 16) ? bb1 : bb2;
    int hw = W * W;
    int y = loc / W, x = loc - y * W;
    const float* bp = bb + (size_t)b * 4 * hw + y * W + x;
    float fs = (float)s;
    float cx = (float)x * fs, cy = (float)y * fs;
    float xc = bp[0] * fs + cx;
    float yc = bp[hw] * fs + cy;
    float wv = exp_np(bp[2 * hw]) * fs;
    float hv = exp_np(bp[3 * hw]) * fs;
    float wv2 = wv * 0.5f, hv2 = hv * 0.5f;
    float4 r;
    r.x = xc - wv2;
    r.y = yc - hv2;
    r.z = xc + wv2;
    r.w = yc + hv2;
    return r;
}

// ---- Kernel A: 4-wide score + label + wave-aggregated compaction ----
// Each thread owns 4 consecutive priors (same level & row: all level sizes and
// widths are multiples of 4) -> float4 loads, 1KB/wave coalescing.
__global__ void __launch_bounds__(256) score_k(
    const float* __restrict__ cls0, const float* __restrict__ cls1, const float* __restrict__ cls2,
    const float* __restrict__ ob0,  const float* __restrict__ ob1,  const float* __restrict__ ob2,
    float* __restrict__ sc, int* __restrict__ labels,
    u64* __restrict__ keys, int* __restrict__ cnts)
{
#pragma clang fp contract(off)
    int b = blockIdx.y;                              // wave-uniform image
    int g = blockIdx.x * 256 + threadIdx.x;          // group of 4 priors
    if (g >= NPRIOR / 4) return;                     // inactive lanes drop from ballots
    int n0 = g * 4;
    int W, s, loc; level_of(n0, W, s, loc);
    const float* cls = (s == 8) ? cls0 : (s == 16) ? cls1 : cls2;
    const float* ob  = (s == 8) ? ob0  : (s == 16) ? ob1  : ob2;
    int hw = W * W;
    int y = loc / W, x = loc - y * W;

    const float* cp = cls + (size_t)b * NCLS * hw + y * W + x;   // 16B aligned
    float4 v = *(const float4*)cp;
    float4 tM;
    tM.x = sigm_np(v.x); tM.y = sigm_np(v.y);
    tM.z = sigm_np(v.z); tM.w = sigm_np(v.w);
    int4 lab = make_int4(0, 0, 0, 0);
    for (int c = 1; c < NCLS; ++c) {
        v = *(const float4*)(cp + (size_t)c * hw);
        float t;
        t = sigm_np(v.x); if (t > tM.x) { tM.x = t; lab.x = c; }
        t = sigm_np(v.y); if (t > tM.y) { tM.y = t; lab.y = c; }
        t = sigm_np(v.z); if (t > tM.z) { tM.z = t; lab.z = c; }
        t = sigm_np(v.w); if (t > tM.w) { tM.w = t; lab.w = c; }
    }
    float4 o = *(const float4*)(ob + (size_t)b * hw + y * W + x);
    float4 sv;
    sv.x = tM.x * sigm_np(o.x);
    sv.y = tM.y * sigm_np(o.y);
    sv.z = tM.z * sigm_np(o.z);
    sv.w = tM.w * sigm_np(o.w);
    float4 scv;
    scv.x = (sv.x >= 0.65f) ? sv.x : 0.0f;
    scv.y = (sv.y >= 0.65f) ? sv.y : 0.0f;
    scv.z = (sv.z >= 0.65f) ? sv.z : 0.0f;
    scv.w = (sv.w >= 0.65f) ? sv.w : 0.0f;
    *(float4*)(sc + (size_t)b * NPRIOR + n0) = scv;
    *(int4*)(labels + (size_t)b * NPRIOR + n0) = lab;

    // wave-aggregated compaction: one atomic per wave per slot (order-free;
    // ranking later restores the exact stable order)
    int lane = threadIdx.x & 63;
#pragma unroll
    for (int e = 0; e < 4; ++e) {
        float se = (e == 0) ? scv.x : (e == 1) ? scv.y : (e == 2) ? scv.z : scv.w;
        bool val = se > 0.0f;
        u64 mb = __ballot(val);
        if (mb) {                                    // wave-uniform branch
            int lead = (int)__builtin_ctzll(mb);
            int base = 0;
            if (lane == lead) base = atomicAdd(&cnts[b * CPAD], (int)__popcll(mb));
            base = __shfl(base, lead);
            if (val) {
                int myoff = (int)__popcll(mb & ((1ull << lane) - 1ull));
                keys[(size_t)b * CAP + base + myoff] =
                    ((u64)__float_as_uint(se) << 32) | (unsigned)(~(unsigned)(n0 + e));
            }
        }
    }
}

// ---- Kernel B: parallel all-pairs rank via readlane broadcast ----
// rank_i = #{j : key_j > key_i}; keys unique => exact stable-sort permutation.
__global__ void __launch_bounds__(256) rank_k(
    const u64* __restrict__ keys, const int* __restrict__ cnts,
    const float* __restrict__ sc, const int* __restrict__ labels,
    const float* __restrict__ bb0, const float* __restrict__ bb1, const float* __restrict__ bb2,
    float4* __restrict__ sel_box, float* __restrict__ sel_score,
    int* __restrict__ sel_label, int* __restrict__ maxbits, u64* __restrict__ vmask)
{
#pragma clang fp contract(off)
    __shared__ float redbuf[256];
    int b = blockIdx.y, chunk = blockIdx.x, tid = threadIdx.x;
    int cn = min(cnts[b * CPAD], CAP);
    int base = chunk * 256;
    if (chunk != 0 && base >= cn) return;   // housekeeping lives in chunk 0

    const u64* keyimg = keys + (size_t)b * CAP;
    const int* labb = labels + (size_t)b * NPRIOR;
    const float* scb = sc + (size_t)b * NPRIOR;
    int lane = tid & 63;

    int i = base + tid;
    u64 ki = (i < cn) ? keyimg[i] : 0ull;
    int rank = 0;
    for (int jb = 0; jb < cn; jb += 64) {
        int j = jb + lane;
        u64 kv = (j < cn) ? keyimg[j] : 0ull;   // coalesced 512B/wave, cache-hot
        unsigned lo = (unsigned)kv, hi = (unsigned)(kv >> 32);
        int lim = cn - jb;                       // uniform
#pragma unroll
        for (int l = 0; l < 64; ++l) {
            unsigned jlo = __builtin_amdgcn_readlane(lo, l);
            unsigned jhi = __builtin_amdgcn_readlane(hi, l);
            u64 kj = ((u64)jhi << 32) | jlo;
            rank += (l < lim && kj > ki) ? 1 : 0;
        }
    }

    float lmax = 0.0f;
    if (i < cn && rank < KTOP) {
        unsigned n = ~(unsigned)(ki & 0xffffffffull);
        float s = __uint_as_float((unsigned)(ki >> 32));
        float4 bx = decode32(b, (int)n, bb0, bb1, bb2);
        sel_box[(size_t)b * 1024 + rank] = bx;
        sel_score[(size_t)b * 1024 + rank] = s;
        sel_label[(size_t)b * 1024 + rank] = labb[n];
        lmax = fmaxf(fmaxf(fabsf(bx.x), fabsf(bx.y)),
                     fmaxf(fabsf(bx.z), fabsf(bx.w)));
    }

    if (chunk == 0) {
        // rare fill path: fewer than K valid -> lowest-index zero-score priors
        if (cn < KTOP && tid == 0) {
            float lm = 0.0f;
            int r = cn;
            for (int n = 0; n < NPRIOR && r < KTOP; ++n) {
                if (scb[n] == 0.0f) {
                    float4 bx = decode32(b, n, bb0, bb1, bb2);
                    sel_box[(size_t)b * 1024 + r] = bx;
                    sel_score[(size_t)b * 1024 + r] = 0.0f;
                    sel_label[(size_t)b * 1024 + r] = labb[n];
                    lm = fmaxf(lm, fmaxf(fmaxf(fabsf(bx.x), fabsf(bx.y)),
                                         fmaxf(fabsf(bx.z), fabsf(bx.w))));
                    ++r;
                }
            }
            lmax = fmaxf(lmax, lm);
        }
        // padding rows 1000..1023: deterministic zeros (excluded via vmask)
        if (tid < 24) {
            sel_box[(size_t)b * 1024 + 1000 + tid] = make_float4(0.f, 0.f, 0.f, 0.f);
            sel_score[(size_t)b * 1024 + 1000 + tid] = 0.0f;
            sel_label[(size_t)b * 1024 + 1000 + tid] = 0;
        }
        // vmask: first min(cn,KTOP) slots valid (closed form)
        if (tid < 16) {
            int vc = min(cn, KTOP);
            int lo = tid * 64;
            u64 m;
            if (vc >= lo + 64)      m = ~0ull;
            else if (vc <= lo)      m = 0ull;
            else                    m = (1ull << (vc - lo)) - 1ull;
            vmask[b * 16 + tid] = m;
        }
    }

    // block max -> one atomicMax per block (f32-as-int valid: values >= 0)
    redbuf[tid] = lmax;
    __syncthreads();
    for (int off = 128; off > 0; off >>= 1) {
        if (tid < off) redbuf[tid] = fmaxf(redbuf[tid], redbuf[tid + off]);
        __syncthreads();
    }
    if (tid == 0) atomicMax(&maxbits[b * CPAD], __float_as_int(redbuf[0]));
}

// ---- Kernel C: TRANSPOSED suppression bitmask via row-ballot ----
// Cmask[(b*1024 + col)*16 + rg] : bit j = "row rg*64+j suppresses col" (row<col)
__global__ void __launch_bounds__(256) build_mask_T(
    const float4* __restrict__ sel_box, const int* __restrict__ sel_label,
    const int* __restrict__ maxbits, u64* __restrict__ Cmask)
{
#pragma clang fp contract(off)
    __shared__ float4 ob[1024];
    __shared__ float ar[1024];
    int b = blockIdx.y, gc = blockIdx.x, tid = threadIdx.x;
    float mc = __int_as_float(maxbits[b * CPAD]) + 1.0f;   // max_coord
    for (int i = tid; i < 1024; i += 256) {
        float4 v = sel_box[(size_t)b * 1024 + i];
        float off = (float)sel_label[(size_t)b * 1024 + i] * mc;
        v.x += off; v.y += off; v.z += off; v.w += off;
        ob[i] = v;
        ar[i] = (v.z - v.x) * (v.w - v.y);   // area of OFFSET box (as ref)
    }
    __syncthreads();
    int wave = tid >> 6, lane = tid & 63;
#pragma unroll
    for (int rgi = 0; rgi < 4; ++rgi) {
        int rg = wave + rgi * 4;          // row group 0..15
        int row = rg * 64 + lane;
        float4 a = ob[row];
        float aa = ar[row];
        for (int cc = 0; cc < 64; ++cc) {
            int col = gc * 64 + cc;
            bool pred = false;
            if (col > row && row < KTOP && col < KTOP) {
                float4 bb = ob[col];      // broadcast (all lanes same addr)
                float tlx = fmaxf(a.x, bb.x), tly = fmaxf(a.y, bb.y);
                float brx = fminf(a.z, bb.z), bry = fminf(a.w, bb.w);
                float w = fmaxf(brx - tlx, 0.0f), h = fmaxf(bry - tly, 0.0f);
                float inter = w * h;
                float uni = (aa + ar[col]) - inter;
                float iou = inter / (uni + 1e-6f);
                pred = iou > 0.65f;
            }
            u64 bits = __ballot(pred);
            if (lane == 0) Cmask[((size_t)b * 1024 + col) * 16 + rg] = bits;
        }
    }
}

// ---- Kernel D: ballot-fixpoint greedy NMS + output ----
__global__ void __launch_bounds__(64) nms_fixpoint_write(
    const u64* __restrict__ Cmask, const u64* __restrict__ vmask,
    const float4* __restrict__ sel_box, const float* __restrict__ sel_score,
    const int* __restrict__ sel_label, float* __restrict__ out)
{
    int b = blockIdx.x, lane = threadIdx.x;
    const u64* Cimg = Cmask + (size_t)b * 1024 * 16;
    u64 Khist[16];
#pragma unroll
    for (int g = 0; g < 16; ++g) {
        int col = g * 64 + lane;
        const u64* ccol = Cimg + (size_t)col * 16;
        bool supp = false;
#pragma unroll
        for (int gp = 0; gp < g; ++gp)
            supp |= (ccol[gp] & Khist[gp]) != 0ull;
        u64 V = vmask[b * 16 + g] & ~__ballot(supp);
        u64 T = ccol[g];
        u64 K = V;
        for (int it = 0; it < 64; ++it) {
            u64 Knew = V & ~__ballot((T & K) != 0ull);
            if (Knew == K) break;        // wave-uniform branch
            K = Knew;
        }
        Khist[g] = K;
    }

    const size_t selo = (size_t)b * 1024;
    float* lab_o = out + (size_t)NB * KTOP * 5;
    float* keep_o = lab_o + (size_t)NB * KTOP;
#pragma unroll
    for (int g = 0; g < 16; ++g) {
        int k = g * 64 + lane;
        if (k >= KTOP) break;
        bool fin = (Khist[g] >> lane) & 1ull;
        float4 bx = sel_box[selo + k];
        float s = sel_score[selo + k];
        int lb = sel_label[selo + k];
        size_t o5 = ((size_t)b * KTOP + k) * 5;
        out[o5 + 0] = fin ? bx.x : 0.0f;
        out[o5 + 1] = fin ? bx.y : 0.0f;
        out[o5 + 2] = fin ? bx.z : 0.0f;
        out[o5 + 3] = fin ? bx.w : 0.0f;
        out[o5 + 4] = fin ? s : 0.0f;
        lab_o[b * KTOP + k] = fin ? (float)lb : -1.0f;
        keep_o[b * KTOP + k] = fin ? 1.0f : 0.0f;
    }
}

extern "C" void kernel_launch(void* const* d_in, const int* in_sizes, int n_in,
                              void* d_out, int out_size, void* d_ws, size_t ws_size,
                              hipStream_t stream) {
    const float* cls0 = (const float*)d_in[0];
    const float* cls1 = (const float*)d_in[1];
    const float* cls2 = (const float*)d_in[2];
    const float* bb0  = (const float*)d_in[3];
    const float* bb1  = (const float*)d_in[4];
    const float* bb2  = (const float*)d_in[5];
    const float* ob0  = (const float*)d_in[6];
    const float* ob1  = (const float*)d_in[7];
    const float* ob2  = (const float*)d_in[8];
    float* out = (float*)d_out;

    char* w = (char*)d_ws;
    size_t used = 0;
    auto alloc = [&](size_t bytes) -> void* {
        void* p = (void*)(w + used);
        used += (bytes + 255) & ~(size_t)255;
        return p;
    };
    float* sc        = (float*)alloc((size_t)NB * NPRIOR * 4);
    int* labels      = (int*)alloc((size_t)NB * NPRIOR * 4);
    u64* keys        = (u64*)alloc((size_t)NB * CAP * 8);
    int* zeroed      = (int*)alloc((size_t)2 * NB * CPAD * 4);   // cnts | maxbits
    float4* sel_box  = (float4*)alloc((size_t)NB * 1024 * 16);
    float* sel_score = (float*)alloc((size_t)NB * 1024 * 4);
    int* sel_label   = (int*)alloc((size_t)NB * 1024 * 4);
    u64* vmask       = (u64*)alloc((size_t)NB * 16 * 8);
    u64* Cmask       = (u64*)alloc((size_t)NB * 1024 * 16 * 8);

    if (used > ws_size) return;   // OOB-write guard

    int* cnts = zeroed;
    int* maxbits = zeroed + NB * CPAD;
    hipMemsetAsync(zeroed, 0, 2 * NB * CPAD * 4, stream);

    score_k<<<dim3((NPRIOR / 4 + 255) / 256, NB), 256, 0, stream>>>(
        cls0, cls1, cls2, ob0, ob1, ob2, sc, labels, keys, cnts);
    rank_k<<<dim3((CAP + 255) / 256, NB), 256, 0, stream>>>(
        keys, cnts, sc, labels, bb0, bb1, bb2,
        sel_box, sel_score, sel_label, maxbits, vmask);
    build_mask_T<<<dim3(16, NB), 256, 0, stream>>>(sel_box, sel_label, maxbits, Cmask);
    nms_fixpoint_write<<<NB, 64, 0, stream>>>(
        Cmask, vmask, sel_box, sel_score, sel_label, out);
}

// Round 11
// 160.621 us; speedup vs baseline: 4.2453x; 1.1642x over previous
//
#include <hip/hip_runtime.h>
#include <stdint.h>

#define NPRIOR 8400
#define NB 32
#define NCLS 80
#define KTOP 1000
#define CAP 8400   // worst-case candidates; never overflows
#define CPAD 16    // ints per counter slot (64B) -> no same-line atomic pileup
#define PCH 8      // class chunks
#define CPC 10     // classes per chunk (PCH*CPC == NCLS)

typedef unsigned long long u64;

// Bit-exact replica of numpy's float32 SIMD exp (Cephes-style, FMA path).
__device__ __forceinline__ float exp_np(float x) {
#pragma clang fp contract(off)
    if (x > 88.72283935546875f) return __builtin_huge_valf();
    if (x < -87.3365478515625f) return 0.0f;
    float q = rintf(x * 1.442695040f);          // v_rndne: round-nearest-even
    float r = fmaf(q, -6.93145752e-1f, x);      // hi split
    r = fmaf(q, -1.42860677e-6f, r);            // lo split
    float p = fmaf(1.9875691500e-4f, r, 1.3981999507e-3f);
    p = fmaf(p, r, 8.3334519073e-3f);
    p = fmaf(p, r, 4.1665795894e-2f);
    p = fmaf(p, r, 1.6666665459e-1f);
    p = fmaf(p, r, 5.0000001201e-1f);
    float r2 = r * r;
    p = fmaf(p, r2, r);
    p = p + 1.0f;
    return ldexpf(p, (int)q);                   // exact 2^q scaling
}
__device__ __forceinline__ float sigm_np(float x) {
#pragma clang fp contract(off)
    float t = exp_np(-x);
    return 1.0f / (1.0f + t);
}

__device__ __forceinline__ void level_of(int n, int& W, int& s, int& loc) {
    if (n < 6400)      { W = 80; s = 8;  loc = n; }
    else if (n < 8000) { W = 40; s = 16; loc = n - 6400; }
    else               { W = 20; s = 32; loc = n - 8000; }
}

__device__ float4 decode32(int b, int n,
                           const float* bb0, const float* bb1, const float* bb2) {
#pragma clang fp contract(off)
    int W, s, loc; level_of(n, W, s, loc);
    const float* bb = (s == 8) ? bb0 : (s == 16) ? bb1 : bb2;
    int hw = W * W;
    int y = loc / W, x = loc - y * W;
    const float* bp = bb + (size_t)b * 4 * hw + y * W + x;
    float fs = (float)s;
    float cx = (float)x * fs, cy = (float)y * fs;
    float xc = bp[0] * fs + cx;
    float yc = bp[hw] * fs + cy;
    float wv = exp_np(bp[2 * hw]) * fs;
    float hv = exp_np(bp[3 * hw]) * fs;
    float wv2 = wv * 0.5f, hv2 = hv * 0.5f;
    float4 r;
    r.x = xc - wv2;
    r.y = yc - hv2;
    r.z = xc + wv2;
    r.w = yc + hv2;
    return r;
}

// pack (sigmoid, class) so u64-max == (max sigmoid, first/smallest class on tie)
__device__ __forceinline__ u64 packkc(float s, int c) {
    return ((u64)__float_as_uint(s) << 32) | (unsigned)(~(unsigned)c);
}

// ---- Kernel A1: per-class-chunk partial (max sigmoid, label) over 10 classes ----
// grid (9, PCH, NB): 2304 blocks -> ~9 waves/SIMD of latency hiding.
__global__ void __launch_bounds__(256) score1_k(
    const float* __restrict__ cls0, const float* __restrict__ cls1, const float* __restrict__ cls2,
    u64* __restrict__ part)
{
#pragma clang fp contract(off)
    int b = blockIdx.z, ch = blockIdx.y;
    int g = blockIdx.x * 256 + threadIdx.x;
    if (g >= NPRIOR / 4) return;
    int n0 = g * 4;
    int W, s, loc; level_of(n0, W, s, loc);
    const float* cls = (s == 8) ? cls0 : (s == 16) ? cls1 : cls2;
    int hw = W * W;
    int y = loc / W, x = loc - y * W;
    const float* cp = cls + (size_t)b * NCLS * hw + y * W + x;   // 16B aligned

    int c0 = ch * CPC;
    float4 v = *(const float4*)(cp + (size_t)c0 * hw);
    u64 k0 = packkc(sigm_np(v.x), c0);
    u64 k1 = packkc(sigm_np(v.y), c0);
    u64 k2 = packkc(sigm_np(v.z), c0);
    u64 k3 = packkc(sigm_np(v.w), c0);
#pragma unroll
    for (int cc = 1; cc < CPC; ++cc) {
        int c = c0 + cc;
        v = *(const float4*)(cp + (size_t)c * hw);
        u64 t;
        t = packkc(sigm_np(v.x), c); if (t > k0) k0 = t;
        t = packkc(sigm_np(v.y), c); if (t > k1) k1 = t;
        t = packkc(sigm_np(v.z), c); if (t > k2) k2 = t;
        t = packkc(sigm_np(v.w), c); if (t > k3) k3 = t;
    }
    u64* p = part + ((size_t)ch * NB + b) * NPRIOR + n0;
    p[0] = k0; p[1] = k1; p[2] = k2; p[3] = k3;
}

// ---- Kernel A2: reduce chunks + obj sigmoid + threshold + compaction ----
__global__ void __launch_bounds__(256) score2_k(
    const float* __restrict__ ob0, const float* __restrict__ ob1, const float* __restrict__ ob2,
    const u64* __restrict__ part,
    float* __restrict__ sc, int* __restrict__ labels,
    u64* __restrict__ keys, int* __restrict__ cnts)
{
#pragma clang fp contract(off)
    int b = blockIdx.y;
    int g = blockIdx.x * 256 + threadIdx.x;
    if (g >= NPRIOR / 4) return;                 // inactive lanes drop from ballots
    int n0 = g * 4;
    int W, s, loc; level_of(n0, W, s, loc);
    const float* ob = (s == 8) ? ob0 : (s == 16) ? ob1 : ob2;
    int hw = W * W;
    int y = loc / W, x = loc - y * W;

    u64 k0 = 0, k1 = 0, k2 = 0, k3 = 0;
#pragma unroll
    for (int ch = 0; ch < PCH; ++ch) {
        const u64* p = part + ((size_t)ch * NB + b) * NPRIOR + n0;
        u64 t0 = p[0], t1 = p[1], t2 = p[2], t3 = p[3];
        if (t0 > k0) k0 = t0;
        if (t1 > k1) k1 = t1;
        if (t2 > k2) k2 = t2;
        if (t3 > k3) k3 = t3;
    }
    float4 tM;
    tM.x = __uint_as_float((unsigned)(k0 >> 32));
    tM.y = __uint_as_float((unsigned)(k1 >> 32));
    tM.z = __uint_as_float((unsigned)(k2 >> 32));
    tM.w = __uint_as_float((unsigned)(k3 >> 32));
    int4 lab;
    lab.x = (int)(~(unsigned)(k0 & 0xffffffffull));
    lab.y = (int)(~(unsigned)(k1 & 0xffffffffull));
    lab.z = (int)(~(unsigned)(k2 & 0xffffffffull));
    lab.w = (int)(~(unsigned)(k3 & 0xffffffffull));

    float4 o = *(const float4*)(ob + (size_t)b * hw + y * W + x);
    float4 sv;
    sv.x = tM.x * sigm_np(o.x);
    sv.y = tM.y * sigm_np(o.y);
    sv.z = tM.z * sigm_np(o.z);
    sv.w = tM.w * sigm_np(o.w);
    float4 scv;
    scv.x = (sv.x >= 0.65f) ? sv.x : 0.0f;
    scv.y = (sv.y >= 0.65f) ? sv.y : 0.0f;
    scv.z = (sv.z >= 0.65f) ? sv.z : 0.0f;
    scv.w = (sv.w >= 0.65f) ? sv.w : 0.0f;
    *(float4*)(sc + (size_t)b * NPRIOR + n0) = scv;
    *(int4*)(labels + (size_t)b * NPRIOR + n0) = lab;

    // wave-aggregated compaction (order-free; ranking restores stable order)
    int lane = threadIdx.x & 63;
#pragma unroll
    for (int e = 0; e < 4; ++e) {
        float se = (e == 0) ? scv.x : (e == 1) ? scv.y : (e == 2) ? scv.z : scv.w;
        bool val = se > 0.0f;
        u64 mb = __ballot(val);
        if (mb) {                                    // wave-uniform branch
            int lead = (int)__builtin_ctzll(mb);
            int base = 0;
            if (lane == lead) base = atomicAdd(&cnts[b * CPAD], (int)__popcll(mb));
            base = __shfl(base, lead);
            if (val) {
                int myoff = (int)__popcll(mb & ((1ull << lane) - 1ull));
                keys[(size_t)b * CAP + base + myoff] =
                    ((u64)__float_as_uint(se) << 32) | (unsigned)(~(unsigned)(n0 + e));
            }
        }
    }
}

// ---- Kernel B: parallel all-pairs rank via readlane broadcast ----
__global__ void __launch_bounds__(256) rank_k(
    const u64* __restrict__ keys, const int* __restrict__ cnts,
    const float* __restrict__ sc, const int* __restrict__ labels,
    const float* __restrict__ bb0, const float* __restrict__ bb1, const float* __restrict__ bb2,
    float4* __restrict__ sel_box, float* __restrict__ sel_score,
    int* __restrict__ sel_label, int* __restrict__ maxbits, u64* __restrict__ vmask)
{
#pragma clang fp contract(off)
    __shared__ float redbuf[256];
    int b = blockIdx.y, chunk = blockIdx.x, tid = threadIdx.x;
    int cn = min(cnts[b * CPAD], CAP);
    int base = chunk * 256;
    if (chunk != 0 && base >= cn) return;   // housekeeping lives in chunk 0

    const u64* keyimg = keys + (size_t)b * CAP;
    const int* labb = labels + (size_t)b * NPRIOR;
    const float* scb = sc + (size_t)b * NPRIOR;
    int lane = tid & 63;

    int i = base + tid;
    u64 ki = (i < cn) ? keyimg[i] : 0ull;
    int rank = 0;
    for (int jb = 0; jb < cn; jb += 64) {
        int j = jb + lane;
        u64 kv = (j < cn) ? keyimg[j] : 0ull;   // coalesced 512B/wave, cache-hot
        unsigned lo = (unsigned)kv, hi = (unsigned)(kv >> 32);
        int lim = cn - jb;                       // uniform
#pragma unroll
        for (int l = 0; l < 64; ++l) {
            unsigned jlo = __builtin_amdgcn_readlane(lo, l);
            unsigned jhi = __builtin_amdgcn_readlane(hi, l);
            u64 kj = ((u64)jhi << 32) | jlo;
            rank += (l < lim && kj > ki) ? 1 : 0;
        }
    }

    float lmax = 0.0f;
    if (i < cn && rank < KTOP) {
        unsigned n = ~(unsigned)(ki & 0xffffffffull);
        float s = __uint_as_float((unsigned)(ki >> 32));
        float4 bx = decode32(b, (int)n, bb0, bb1, bb2);
        sel_box[(size_t)b * 1024 + rank] = bx;
        sel_score[(size_t)b * 1024 + rank] = s;
        sel_label[(size_t)b * 1024 + rank] = labb[n];
        lmax = fmaxf(fmaxf(fabsf(bx.x), fabsf(bx.y)),
                     fmaxf(fabsf(bx.z), fabsf(bx.w)));
    }

    if (chunk == 0) {
        // rare fill path: fewer than K valid -> lowest-index zero-score priors
        if (cn < KTOP && tid == 0) {
            float lm = 0.0f;
            int r = cn;
            for (int n = 0; n < NPRIOR && r < KTOP; ++n) {
                if (scb[n] == 0.0f) {
                    float4 bx = decode32(b, n, bb0, bb1, bb2);
                    sel_box[(size_t)b * 1024 + r] = bx;
                    sel_score[(size_t)b * 1024 + r] = 0.0f;
                    sel_label[(size_t)b * 1024 + r] = labb[n];
                    lm = fmaxf(lm, fmaxf(fmaxf(fabsf(bx.x), fabsf(bx.y)),
                                         fmaxf(fabsf(bx.z), fabsf(bx.w))));
                    ++r;
                }
            }
            lmax = fmaxf(lmax, lm);
        }
        if (tid < 24) {   // padding rows 1000..1023 (excluded via vmask)
            sel_box[(size_t)b * 1024 + 1000 + tid] = make_float4(0.f, 0.f, 0.f, 0.f);
            sel_score[(size_t)b * 1024 + 1000 + tid] = 0.0f;
            sel_label[(size_t)b * 1024 + 1000 + tid] = 0;
        }
        if (tid < 16) {   // vmask closed form
            int vc = min(cn, KTOP);
            int lo = tid * 64;
            u64 m;
            if (vc >= lo + 64)      m = ~0ull;
            else if (vc <= lo)      m = 0ull;
            else                    m = (1ull << (vc - lo)) - 1ull;
            vmask[b * 16 + tid] = m;
        }
    }

    redbuf[tid] = lmax;
    __syncthreads();
    for (int off = 128; off > 0; off >>= 1) {
        if (tid < off) redbuf[tid] = fmaxf(redbuf[tid], redbuf[tid + off]);
        __syncthreads();
    }
    if (tid == 0) atomicMax(&maxbits[b * CPAD], __float_as_int(redbuf[0]));
}

// ---- Kernel C: TRANSPOSED suppression bitmask via row-ballot ----
__global__ void __launch_bounds__(256) build_mask_T(
    const float4* __restrict__ sel_box, const int* __restrict__ sel_label,
    const int* __restrict__ maxbits, u64* __restrict__ Cmask)
{
#pragma clang fp contract(off)
    __shared__ float4 ob[1024];
    __shared__ float ar[1024];
    int b = blockIdx.y, gc = blockIdx.x, tid = threadIdx.x;
    float mc = __int_as_float(maxbits[b * CPAD]) + 1.0f;   // max_coord
    for (int i = tid; i < 1024; i += 256) {
        float4 v = sel_box[(size_t)b * 1024 + i];
        float off = (float)sel_label[(size_t)b * 1024 + i] * mc;
        v.x += off; v.y += off; v.z += off; v.w += off;
        ob[i] = v;
        ar[i] = (v.z - v.x) * (v.w - v.y);   // area of OFFSET box (as ref)
    }
    __syncthreads();
    int wave = tid >> 6, lane = tid & 63;
#pragma unroll
    for (int rgi = 0; rgi < 4; ++rgi) {
        int rg = wave + rgi * 4;          // row group 0..15
        int row = rg * 64 + lane;
        float4 a = ob[row];
        float aa = ar[row];
        for (int cc = 0; cc < 64; ++cc) {
            int col = gc * 64 + cc;
            bool pred = false;
            if (col > row && row < KTOP && col < KTOP) {
                float4 bb = ob[col];      // broadcast (all lanes same addr)
                float tlx = fmaxf(a.x, bb.x), tly = fmaxf(a.y, bb.y);
                float brx = fminf(a.z, bb.z), bry = fminf(a.w, bb.w);
                float w = fmaxf(brx - tlx, 0.0f), h = fmaxf(bry - tly, 0.0f);
                float inter = w * h;
                float uni = (aa + ar[col]) - inter;
                float iou = inter / (uni + 1e-6f);
                pred = iou > 0.65f;
            }
            u64 bits = __ballot(pred);
            if (lane == 0) Cmask[((size_t)b * 1024 + col) * 16 + rg] = bits;
        }
    }
}

// ---- Kernel D: ballot-fixpoint greedy NMS + output ----
__global__ void __launch_bounds__(64) nms_fixpoint_write(
    const u64* __restrict__ Cmask, const u64* __restrict__ vmask,
    const float4* __restrict__ sel_box, const float* __restrict__ sel_score,
    const int* __restrict__ sel_label, float* __restrict__ out)
{
    int b = blockIdx.x, lane = threadIdx.x;
    const u64* Cimg = Cmask + (size_t)b * 1024 * 16;
    u64 Khist[16];
#pragma unroll
    for (int g = 0; g < 16; ++g) {
        int col = g * 64 + lane;
        const u64* ccol = Cimg + (size_t)col * 16;
        bool supp = false;
#pragma unroll
        for (int gp = 0; gp < g; ++gp)
            supp |= (ccol[gp] & Khist[gp]) != 0ull;
        u64 V = vmask[b * 16 + g] & ~__ballot(supp);
        u64 T = ccol[g];
        u64 K = V;
        for (int it = 0; it < 64; ++it) {
            u64 Knew = V & ~__ballot((T & K) != 0ull);
            if (Knew == K) break;        // wave-uniform branch
            K = Knew;
        }
        Khist[g] = K;
    }

    const size_t selo = (size_t)b * 1024;
    float* lab_o = out + (size_t)NB * KTOP * 5;
    float* keep_o = lab_o + (size_t)NB * KTOP;
#pragma unroll
    for (int g = 0; g < 16; ++g) {
        int k = g * 64 + lane;
        if (k >= KTOP) break;
        bool fin = (Khist[g] >> lane) & 1ull;
        float4 bx = sel_box[selo + k];
        float s = sel_score[selo + k];
        int lb = sel_label[selo + k];
        size_t o5 = ((size_t)b * KTOP + k) * 5;
        out[o5 + 0] = fin ? bx.x : 0.0f;
        out[o5 + 1] = fin ? bx.y : 0.0f;
        out[o5 + 2] = fin ? bx.z : 0.0f;
        out[o5 + 3] = fin ? bx.w : 0.0f;
        out[o5 + 4] = fin ? s : 0.0f;
        lab_o[b * KTOP + k] = fin ? (float)lb : -1.0f;
        keep_o[b * KTOP + k] = fin ? 1.0f : 0.0f;
    }
}

extern "C" void kernel_launch(void* const* d_in, const int* in_sizes, int n_in,
                              void* d_out, int out_size, void* d_ws, size_t ws_size,
                              hipStream_t stream) {
    const float* cls0 = (const float*)d_in[0];
    const float* cls1 = (const float*)d_in[1];
    const float* cls2 = (const float*)d_in[2];
    const float* bb0  = (const float*)d_in[3];
    const float* bb1  = (const float*)d_in[4];
    const float* bb2  = (const float*)d_in[5];
    const float* ob0  = (const float*)d_in[6];
    const float* ob1  = (const float*)d_in[7];
    const float* ob2  = (const float*)d_in[8];
    float* out = (float*)d_out;

    char* w = (char*)d_ws;
    size_t used = 0;
    auto alloc = [&](size_t bytes) -> void* {
        void* p = (void*)(w + used);
        used += (bytes + 255) & ~(size_t)255;
        return p;
    };
    float* sc        = (float*)alloc((size_t)NB * NPRIOR * 4);
    int* labels      = (int*)alloc((size_t)NB * NPRIOR * 4);
    u64* keys        = (u64*)alloc((size_t)NB * CAP * 8);
    u64* part        = (u64*)alloc((size_t)PCH * NB * NPRIOR * 8);
    int* zeroed      = (int*)alloc((size_t)2 * NB * CPAD * 4);   // cnts | maxbits
    float4* sel_box  = (float4*)alloc((size_t)NB * 1024 * 16);
    float* sel_score = (float*)alloc((size_t)NB * 1024 * 4);
    int* sel_label   = (int*)alloc((size_t)NB * 1024 * 4);
    u64* vmask       = (u64*)alloc((size_t)NB * 16 * 8);
    u64* Cmask       = (u64*)alloc((size_t)NB * 1024 * 16 * 8);

    if (used > ws_size) return;   // OOB-write guard

    int* cnts = zeroed;
    int* maxbits = zeroed + NB * CPAD;
    hipMemsetAsync(zeroed, 0, 2 * NB * CPAD * 4, stream);

    score1_k<<<dim3((NPRIOR / 4 + 255) / 256, PCH, NB), 256, 0, stream>>>(
        cls0, cls1, cls2, part);
    score2_k<<<dim3((NPRIOR / 4 + 255) / 256, NB), 256, 0, stream>>>(
        ob0, ob1, ob2, part, sc, labels, keys, cnts);
    rank_k<<<dim3((CAP + 255) / 256, NB), 256, 0, stream>>>(
        keys, cnts, sc, labels, bb0, bb1, bb2,
        sel_box, sel_score, sel_label, maxbits, vmask);
    build_mask_T<<<dim3(16, NB), 256, 0, stream>>>(sel_box, sel_label, maxbits, Cmask);
    nms_fixpoint_write<<<NB, 64, 0, stream>>>(
        Cmask, vmask, sel_box, sel_score, sel_label, out);
}

// Round 12
// 131.775 us; speedup vs baseline: 5.1746x; 1.2189x over previous
//
#include <hip/hip_runtime.h>
#include <stdint.h>

#define NPRIOR 8400
#define NB 32
#define NCLS 80
#define KTOP 1000
#define CAP 8400   // worst-case candidates; never overflows
#define CPAD 16    // ints per counter slot (64B) -> no same-line atomic pileup
#define PCH 8      // class chunks
#define CPC 10     // classes per chunk (PCH*CPC == NCLS)

typedef unsigned long long u64;

// Bit-exact replica of numpy's float32 SIMD exp (Cephes-style, FMA path).
__device__ __forceinline__ float exp_np(float x) {
#pragma clang fp contract(off)
    if (x > 88.72283935546875f) return __builtin_huge_valf();
    if (x < -87.3365478515625f) return 0.0f;
    float q = rintf(x * 1.442695040f);          // v_rndne: round-nearest-even
    float r = fmaf(q, -6.93145752e-1f, x);      // hi split
    r = fmaf(q, -1.42860677e-6f, r);            // lo split
    float p = fmaf(1.9875691500e-4f, r, 1.3981999507e-3f);
    p = fmaf(p, r, 8.3334519073e-3f);
    p = fmaf(p, r, 4.1665795894e-2f);
    p = fmaf(p, r, 1.6666665459e-1f);
    p = fmaf(p, r, 5.0000001201e-1f);
    float r2 = r * r;
    p = fmaf(p, r2, r);
    p = p + 1.0f;
    return ldexpf(p, (int)q);                   // exact 2^q scaling
}
__device__ __forceinline__ float sigm_np(float x) {
#pragma clang fp contract(off)
    float t = exp_np(-x);
    return 1.0f / (1.0f + t);
}

__device__ __forceinline__ void level_of(int n, int& W, int& s, int& loc) {
    if (n < 6400)      { W = 80; s = 8;  loc = n; }
    else if (n < 8000) { W = 40; s = 16; loc = n - 6400; }
    else               { W = 20; s = 32; loc = n - 8000; }
}

__device__ float4 decode32(int b, int n,
                           const float* bb0, const float* bb1, const float* bb2) {
#pragma clang fp contract(off)
    int W, s, loc; level_of(n, W, s, loc);
    const float* bb = (s == 8) ? bb0 : (s == 16) ? bb1 : bb2;
    int hw = W * W;
    int y = loc / W, x = loc - y * W;
    const float* bp = bb + (size_t)b * 4 * hw + y * W + x;
    float fs = (float)s;
    float cx = (float)x * fs, cy = (float)y * fs;
    float xc = bp[0] * fs + cx;
    float yc = bp[hw] * fs + cy;
    float wv = exp_np(bp[2 * hw]) * fs;
    float hv = exp_np(bp[3 * hw]) * fs;
    float wv2 = wv * 0.5f, hv2 = hv * 0.5f;
    float4 r;
    r.x = xc - wv2;
    r.y = yc - hv2;
    r.z = xc + wv2;
    r.w = yc + hv2;
    return r;
}

// pack (sigmoid, class) so u64-max == (max sigmoid, first/smallest class on tie)
__device__ __forceinline__ u64 packkc(float s, int c) {
    return ((u64)__float_as_uint(s) << 32) | (unsigned)(~(unsigned)c);
}

// ---- Kernel A1: per-class-chunk partial (max sigmoid, label) over 10 classes ----
__global__ void __launch_bounds__(256) score1_k(
    const float* __restrict__ cls0, const float* __restrict__ cls1, const float* __restrict__ cls2,
    u64* __restrict__ part)
{
#pragma clang fp contract(off)
    int b = blockIdx.z, ch = blockIdx.y;
    int g = blockIdx.x * 256 + threadIdx.x;
    if (g >= NPRIOR / 4) return;
    int n0 = g * 4;
    int W, s, loc; level_of(n0, W, s, loc);
    const float* cls = (s == 8) ? cls0 : (s == 16) ? cls1 : cls2;
    int hw = W * W;
    int y = loc / W, x = loc - y * W;
    const float* cp = cls + (size_t)b * NCLS * hw + y * W + x;   // 16B aligned

    int c0 = ch * CPC;
    float4 v = *(const float4*)(cp + (size_t)c0 * hw);
    u64 k0 = packkc(sigm_np(v.x), c0);
    u64 k1 = packkc(sigm_np(v.y), c0);
    u64 k2 = packkc(sigm_np(v.z), c0);
    u64 k3 = packkc(sigm_np(v.w), c0);
#pragma unroll
    for (int cc = 1; cc < CPC; ++cc) {
        int c = c0 + cc;
        v = *(const float4*)(cp + (size_t)c * hw);
        u64 t;
        t = packkc(sigm_np(v.x), c); if (t > k0) k0 = t;
        t = packkc(sigm_np(v.y), c); if (t > k1) k1 = t;
        t = packkc(sigm_np(v.z), c); if (t > k2) k2 = t;
        t = packkc(sigm_np(v.w), c); if (t > k3) k3 = t;
    }
    u64* p = part + ((size_t)ch * NB + b) * NPRIOR + n0;
    p[0] = k0; p[1] = k1; p[2] = k2; p[3] = k3;
}

// ---- Kernel A2: reduce chunks + obj sigmoid + threshold + compaction ----
__global__ void __launch_bounds__(256) score2_k(
    const float* __restrict__ ob0, const float* __restrict__ ob1, const float* __restrict__ ob2,
    const u64* __restrict__ part,
    float* __restrict__ sc, int* __restrict__ labels,
    u64* __restrict__ keys, int* __restrict__ cnts)
{
#pragma clang fp contract(off)
    int b = blockIdx.y;
    int g = blockIdx.x * 256 + threadIdx.x;
    if (g >= NPRIOR / 4) return;                 // inactive lanes drop from ballots
    int n0 = g * 4;
    int W, s, loc; level_of(n0, W, s, loc);
    const float* ob = (s == 8) ? ob0 : (s == 16) ? ob1 : ob2;
    int hw = W * W;
    int y = loc / W, x = loc - y * W;

    u64 k0 = 0, k1 = 0, k2 = 0, k3 = 0;
#pragma unroll
    for (int ch = 0; ch < PCH; ++ch) {
        const u64* p = part + ((size_t)ch * NB + b) * NPRIOR + n0;
        u64 t0 = p[0], t1 = p[1], t2 = p[2], t3 = p[3];
        if (t0 > k0) k0 = t0;
        if (t1 > k1) k1 = t1;
        if (t2 > k2) k2 = t2;
        if (t3 > k3) k3 = t3;
    }
    float4 tM;
    tM.x = __uint_as_float((unsigned)(k0 >> 32));
    tM.y = __uint_as_float((unsigned)(k1 >> 32));
    tM.z = __uint_as_float((unsigned)(k2 >> 32));
    tM.w = __uint_as_float((unsigned)(k3 >> 32));
    int4 lab;
    lab.x = (int)(~(unsigned)(k0 & 0xffffffffull));
    lab.y = (int)(~(unsigned)(k1 & 0xffffffffull));
    lab.z = (int)(~(unsigned)(k2 & 0xffffffffull));
    lab.w = (int)(~(unsigned)(k3 & 0xffffffffull));

    float4 o = *(const float4*)(ob + (size_t)b * hw + y * W + x);
    float4 sv;
    sv.x = tM.x * sigm_np(o.x);
    sv.y = tM.y * sigm_np(o.y);
    sv.z = tM.z * sigm_np(o.z);
    sv.w = tM.w * sigm_np(o.w);
    float4 scv;
    scv.x = (sv.x >= 0.65f) ? sv.x : 0.0f;
    scv.y = (sv.y >= 0.65f) ? sv.y : 0.0f;
    scv.z = (sv.z >= 0.65f) ? sv.z : 0.0f;
    scv.w = (sv.w >= 0.65f) ? sv.w : 0.0f;
    *(float4*)(sc + (size_t)b * NPRIOR + n0) = scv;
    *(int4*)(labels + (size_t)b * NPRIOR + n0) = lab;

    // wave-aggregated compaction (order-free; ranking restores stable order)
    int lane = threadIdx.x & 63;
#pragma unroll
    for (int e = 0; e < 4; ++e) {
        float se = (e == 0) ? scv.x : (e == 1) ? scv.y : (e == 2) ? scv.z : scv.w;
        bool val = se > 0.0f;
        u64 mb = __ballot(val);
        if (mb) {                                    // wave-uniform branch
            int lead = (int)__builtin_ctzll(mb);
            int base = 0;
            if (lane == lead) base = atomicAdd(&cnts[b * CPAD], (int)__popcll(mb));
            base = __shfl(base, lead);
            if (val) {
                int myoff = (int)__popcll(mb & ((1ull << lane) - 1ull));
                keys[(size_t)b * CAP + base + myoff] =
                    ((u64)__float_as_uint(se) << 32) | (unsigned)(~(unsigned)(n0 + e));
            }
        }
    }
}

// ---- Kernel B1: 2D-tiled all-pairs partial rank (atomicAdd accumulate) ----
// rank_i = #{j : key_j > key_i}, accumulated over 256-wide j tiles.
__global__ void __launch_bounds__(256) rank_part(
    const u64* __restrict__ keys, const int* __restrict__ cnts,
    int* __restrict__ rankbuf)
{
    int b = blockIdx.y, tid = threadIdx.x;
    int cn = min(cnts[b * CPAD], CAP);
    int nt = (cn + 255) >> 8;                    // tiles per dimension
    int ntt = nt * nt;
    const u64* keyimg = keys + (size_t)b * CAP;
    int lane = tid & 63;

    for (int t = blockIdx.x; t < ntt; t += gridDim.x) {
        int it = t / nt, jt = t - it * nt;
        int i = it * 256 + tid;
        u64 ki = (i < cn) ? keyimg[i] : ~0ull;   // sentinel: counts stay 0
        int rank = 0;
        int jbase = jt * 256;
        int jend = min(jbase + 256, cn);
        for (int jb = jbase; jb < jend; jb += 64) {
            int j = jb + lane;
            u64 kv = (j < cn) ? keyimg[j] : 0ull;   // coalesced, cache-hot
            unsigned lo = (unsigned)kv, hi = (unsigned)(kv >> 32);
            int lim = jend - jb;                     // uniform
#pragma unroll
            for (int l = 0; l < 64; ++l) {
                unsigned jlo = __builtin_amdgcn_readlane(lo, l);
                unsigned jhi = __builtin_amdgcn_readlane(hi, l);
                u64 kj = ((u64)jhi << 32) | jlo;
                rank += (l < lim && kj > ki) ? 1 : 0;
            }
        }
        if (i < cn && rank > 0) atomicAdd(&rankbuf[(size_t)b * CAP + i], rank);
    }
}

// ---- Kernel B2: scatter by rank + decode + housekeeping ----
__global__ void __launch_bounds__(256) scatter_k(
    const u64* __restrict__ keys, const int* __restrict__ cnts,
    const int* __restrict__ rankbuf,
    const float* __restrict__ sc, const int* __restrict__ labels,
    const float* __restrict__ bb0, const float* __restrict__ bb1, const float* __restrict__ bb2,
    float4* __restrict__ sel_box, float* __restrict__ sel_score,
    int* __restrict__ sel_label, int* __restrict__ maxbits, u64* __restrict__ vmask)
{
#pragma clang fp contract(off)
    __shared__ float redbuf[256];
    int b = blockIdx.y, chunk = blockIdx.x, tid = threadIdx.x;
    int cn = min(cnts[b * CPAD], CAP);
    int base = chunk * 256;
    if (chunk != 0 && base >= cn) return;   // housekeeping lives in chunk 0

    const u64* keyimg = keys + (size_t)b * CAP;
    const int* labb = labels + (size_t)b * NPRIOR;
    const float* scb = sc + (size_t)b * NPRIOR;

    int i = base + tid;
    float lmax = 0.0f;
    if (i < cn) {
        int rank = rankbuf[(size_t)b * CAP + i];
        if (rank < KTOP) {
            u64 ki = keyimg[i];
            unsigned n = ~(unsigned)(ki & 0xffffffffull);
            float s = __uint_as_float((unsigned)(ki >> 32));
            float4 bx = decode32(b, (int)n, bb0, bb1, bb2);
            sel_box[(size_t)b * 1024 + rank] = bx;
            sel_score[(size_t)b * 1024 + rank] = s;
            sel_label[(size_t)b * 1024 + rank] = labb[n];
            lmax = fmaxf(fmaxf(fabsf(bx.x), fabsf(bx.y)),
                         fmaxf(fabsf(bx.z), fabsf(bx.w)));
        }
    }

    if (chunk == 0) {
        // rare fill path: fewer than K valid -> lowest-index zero-score priors
        if (cn < KTOP && tid == 0) {
            float lm = 0.0f;
            int r = cn;
            for (int n = 0; n < NPRIOR && r < KTOP; ++n) {
                if (scb[n] == 0.0f) {
                    float4 bx = decode32(b, n, bb0, bb1, bb2);
                    sel_box[(size_t)b * 1024 + r] = bx;
                    sel_score[(size_t)b * 1024 + r] = 0.0f;
                    sel_label[(size_t)b * 1024 + r] = labb[n];
                    lm = fmaxf(lm, fmaxf(fmaxf(fabsf(bx.x), fabsf(bx.y)),
                                         fmaxf(fabsf(bx.z), fabsf(bx.w))));
                    ++r;
                }
            }
            lmax = fmaxf(lmax, lm);
        }
        if (tid < 24) {   // padding rows 1000..1023 (excluded via vmask)
            sel_box[(size_t)b * 1024 + 1000 + tid] = make_float4(0.f, 0.f, 0.f, 0.f);
            sel_score[(size_t)b * 1024 + 1000 + tid] = 0.0f;
            sel_label[(size_t)b * 1024 + 1000 + tid] = 0;
        }
        if (tid < 16) {   // vmask closed form
            int vc = min(cn, KTOP);
            int lo = tid * 64;
            u64 m;
            if (vc >= lo + 64)      m = ~0ull;
            else if (vc <= lo)      m = 0ull;
            else                    m = (1ull << (vc - lo)) - 1ull;
            vmask[b * 16 + tid] = m;
        }
    }

    redbuf[tid] = lmax;
    __syncthreads();
    for (int off = 128; off > 0; off >>= 1) {
        if (tid < off) redbuf[tid] = fmaxf(redbuf[tid], redbuf[tid + off]);
        __syncthreads();
    }
    if (tid == 0) atomicMax(&maxbits[b * CPAD], __float_as_int(redbuf[0]));
}

// ---- Kernel C: TRANSPOSED suppression bitmask via row-ballot ----
__global__ void __launch_bounds__(256) build_mask_T(
    const float4* __restrict__ sel_box, const int* __restrict__ sel_label,
    const int* __restrict__ maxbits, u64* __restrict__ Cmask)
{
#pragma clang fp contract(off)
    __shared__ float4 ob[1024];
    __shared__ float ar[1024];
    int b = blockIdx.y, gc = blockIdx.x, tid = threadIdx.x;
    float mc = __int_as_float(maxbits[b * CPAD]) + 1.0f;   // max_coord
    for (int i = tid; i < 1024; i += 256) {
        float4 v = sel_box[(size_t)b * 1024 + i];
        float off = (float)sel_label[(size_t)b * 1024 + i] * mc;
        v.x += off; v.y += off; v.z += off; v.w += off;
        ob[i] = v;
        ar[i] = (v.z - v.x) * (v.w - v.y);   // area of OFFSET box (as ref)
    }
    __syncthreads();
    int wave = tid >> 6, lane = tid & 63;
#pragma unroll
    for (int rgi = 0; rgi < 4; ++rgi) {
        int rg = wave + rgi * 4;          // row group 0..15
        int row = rg * 64 + lane;
        float4 a = ob[row];
        float aa = ar[row];
        for (int cc = 0; cc < 64; ++cc) {
            int col = gc * 64 + cc;
            bool pred = false;
            if (col > row && row < KTOP && col < KTOP) {
                float4 bb = ob[col];      // broadcast (all lanes same addr)
                float tlx = fmaxf(a.x, bb.x), tly = fmaxf(a.y, bb.y);
                float brx = fminf(a.z, bb.z), bry = fminf(a.w, bb.w);
                float w = fmaxf(brx - tlx, 0.0f), h = fmaxf(bry - tly, 0.0f);
                float inter = w * h;
                float uni = (aa + ar[col]) - inter;
                float iou = inter / (uni + 1e-6f);
                pred = iou > 0.65f;
            }
            u64 bits = __ballot(pred);
            if (lane == 0) Cmask[((size_t)b * 1024 + col) * 16 + rg] = bits;
        }
    }
}

// ---- Kernel D: ballot-fixpoint greedy NMS + output ----
__global__ void __launch_bounds__(64) nms_fixpoint_write(
    const u64* __restrict__ Cmask, const u64* __restrict__ vmask,
    const float4* __restrict__ sel_box, const float* __restrict__ sel_score,
    const int* __restrict__ sel_label, float* __restrict__ out)
{
    int b = blockIdx.x, lane = threadIdx.x;
    const u64* Cimg = Cmask + (size_t)b * 1024 * 16;
    u64 Khist[16];
#pragma unroll
    for (int g = 0; g < 16; ++g) {
        int col = g * 64 + lane;
        const u64* ccol = Cimg + (size_t)col * 16;
        bool supp = false;
#pragma unroll
        for (int gp = 0; gp < g; ++gp)
            supp |= (ccol[gp] & Khist[gp]) != 0ull;
        u64 V = vmask[b * 16 + g] & ~__ballot(supp);
        u64 T = ccol[g];
        u64 K = V;
        for (int it = 0; it < 64; ++it) {
            u64 Knew = V & ~__ballot((T & K) != 0ull);
            if (Knew == K) break;        // wave-uniform branch
            K = Knew;
        }
        Khist[g] = K;
    }

    const size_t selo = (size_t)b * 1024;
    float* lab_o = out + (size_t)NB * KTOP * 5;
    float* keep_o = lab_o + (size_t)NB * KTOP;
#pragma unroll
    for (int g = 0; g < 16; ++g) {
        int k = g * 64 + lane;
        if (k >= KTOP) break;
        bool fin = (Khist[g] >> lane) & 1ull;
        float4 bx = sel_box[selo + k];
        float s = sel_score[selo + k];
        int lb = sel_label[selo + k];
        size_t o5 = ((size_t)b * KTOP + k) * 5;
        out[o5 + 0] = fin ? bx.x : 0.0f;
        out[o5 + 1] = fin ? bx.y : 0.0f;
        out[o5 + 2] = fin ? bx.z : 0.0f;
        out[o5 + 3] = fin ? bx.w : 0.0f;
        out[o5 + 4] = fin ? s : 0.0f;
        lab_o[b * KTOP + k] = fin ? (float)lb : -1.0f;
        keep_o[b * KTOP + k] = fin ? 1.0f : 0.0f;
    }
}

extern "C" void kernel_launch(void* const* d_in, const int* in_sizes, int n_in,
                              void* d_out, int out_size, void* d_ws, size_t ws_size,
                              hipStream_t stream) {
    const float* cls0 = (const float*)d_in[0];
    const float* cls1 = (const float*)d_in[1];
    const float* cls2 = (const float*)d_in[2];
    const float* bb0  = (const float*)d_in[3];
    const float* bb1  = (const float*)d_in[4];
    const float* bb2  = (const float*)d_in[5];
    const float* ob0  = (const float*)d_in[6];
    const float* ob1  = (const float*)d_in[7];
    const float* ob2  = (const float*)d_in[8];
    float* out = (float*)d_out;

    char* w = (char*)d_ws;
    size_t used = 0;
    auto alloc = [&](size_t bytes) -> void* {
        void* p = (void*)(w + used);
        used += (bytes + 255) & ~(size_t)255;
        return p;
    };
    float* sc        = (float*)alloc((size_t)NB * NPRIOR * 4);
    int* labels      = (int*)alloc((size_t)NB * NPRIOR * 4);
    u64* keys        = (u64*)alloc((size_t)NB * CAP * 8);
    u64* part        = (u64*)alloc((size_t)PCH * NB * NPRIOR * 8);
    int* zeroed      = (int*)alloc((size_t)(2 * NB * CPAD + NB * CAP) * 4); // cnts|maxbits|rankbuf
    float4* sel_box  = (float4*)alloc((size_t)NB * 1024 * 16);
    float* sel_score = (float*)alloc((size_t)NB * 1024 * 4);
    int* sel_label   = (int*)alloc((size_t)NB * 1024 * 4);
    u64* vmask       = (u64*)alloc((size_t)NB * 16 * 8);
    u64* Cmask       = (u64*)alloc((size_t)NB * 1024 * 16 * 8);

    if (used > ws_size) return;   // OOB-write guard

    int* cnts = zeroed;
    int* maxbits = zeroed + NB * CPAD;
    int* rankbuf = zeroed + 2 * NB * CPAD;
    hipMemsetAsync(zeroed, 0, (size_t)(2 * NB * CPAD + NB * CAP) * 4, stream);

    score1_k<<<dim3((NPRIOR / 4 + 255) / 256, PCH, NB), 256, 0, stream>>>(
        cls0, cls1, cls2, part);
    score2_k<<<dim3((NPRIOR / 4 + 255) / 256, NB), 256, 0, stream>>>(
        ob0, ob1, ob2, part, sc, labels, keys, cnts);
    rank_part<<<dim3(64, NB), 256, 0, stream>>>(keys, cnts, rankbuf);
    scatter_k<<<dim3((CAP + 255) / 256, NB), 256, 0, stream>>>(
        keys, cnts, rankbuf, sc, labels, bb0, bb1, bb2,
        sel_box, sel_score, sel_label, maxbits, vmask);
    build_mask_T<<<dim3(16, NB), 256, 0, stream>>>(sel_box, sel_label, maxbits, Cmask);
    nms_fixpoint_write<<<NB, 64, 0, stream>>>(
        Cmask, vmask, sel_box, sel_score, sel_label, out);
}

// Round 13
// 111.268 us; speedup vs baseline: 6.1283x; 1.1843x over previous
//
#include <hip/hip_runtime.h>
#include <stdint.h>

#define NPRIOR 8400
#define NB 32
#define NCLS 80
#define KTOP 1000
#define CAP 8400   // worst-case candidates; never overflows
#define CPAD 16    // ints per counter slot (64B) -> no same-line atomic pileup
#define PCH 8      // class chunks
#define CPC 10     // classes per chunk (PCH*CPC == NCLS)

typedef unsigned long long u64;

// Bit-exact replica of numpy's float32 SIMD exp (Cephes-style, FMA path).
__device__ __forceinline__ float exp_np(float x) {
#pragma clang fp contract(off)
    if (x > 88.72283935546875f) return __builtin_huge_valf();
    if (x < -87.3365478515625f) return 0.0f;
    float q = rintf(x * 1.442695040f);          // v_rndne: round-nearest-even
    float r = fmaf(q, -6.93145752e-1f, x);      // hi split
    r = fmaf(q, -1.42860677e-6f, r);            // lo split
    float p = fmaf(1.9875691500e-4f, r, 1.3981999507e-3f);
    p = fmaf(p, r, 8.3334519073e-3f);
    p = fmaf(p, r, 4.1665795894e-2f);
    p = fmaf(p, r, 1.6666665459e-1f);
    p = fmaf(p, r, 5.0000001201e-1f);
    float r2 = r * r;
    p = fmaf(p, r2, r);
    p = p + 1.0f;
    return ldexpf(p, (int)q);                   // exact 2^q scaling
}
__device__ __forceinline__ float sigm_np(float x) {
#pragma clang fp contract(off)
    float t = exp_np(-x);
    return 1.0f / (1.0f + t);
}

__device__ __forceinline__ void level_of(int n, int& W, int& s, int& loc) {
    if (n < 6400)      { W = 80; s = 8;  loc = n; }
    else if (n < 8000) { W = 40; s = 16; loc = n - 6400; }
    else               { W = 20; s = 32; loc = n - 8000; }
}

__device__ float4 decode32(int b, int n,
                           const float* bb0, const float* bb1, const float* bb2) {
#pragma clang fp contract(off)
    int W, s, loc; level_of(n, W, s, loc);
    const float* bb = (s == 8) ? bb0 : (s == 16) ? bb1 : bb2;
    int hw = W * W;
    int y = loc / W, x = loc - y * W;
    const float* bp = bb + (size_t)b * 4 * hw + y * W + x;
    float fs = (float)s;
    float cx = (float)x * fs, cy = (float)y * fs;
    float xc = bp[0] * fs + cx;
    float yc = bp[hw] * fs + cy;
    float wv = exp_np(bp[2 * hw]) * fs;
    float hv = exp_np(bp[3 * hw]) * fs;
    float wv2 = wv * 0.5f, hv2 = hv * 0.5f;
    float4 r;
    r.x = xc - wv2;
    r.y = yc - hv2;
    r.z = xc + wv2;
    r.w = yc + hv2;
    return r;
}

// pack (sigmoid, class) so u64-max == (max sigmoid, first/smallest class on tie)
__device__ __forceinline__ u64 packkc(float s, int c) {
    return ((u64)__float_as_uint(s) << 32) | (unsigned)(~(unsigned)c);
}

// ---- Kernel A1: per-class-chunk partial (max sigmoid, label) over 10 classes ----
__global__ void __launch_bounds__(256) score1_k(
    const float* __restrict__ cls0, const float* __restrict__ cls1, const float* __restrict__ cls2,
    u64* __restrict__ part)
{
#pragma clang fp contract(off)
    int b = blockIdx.z, ch = blockIdx.y;
    int g = blockIdx.x * 256 + threadIdx.x;
    if (g >= NPRIOR / 4) return;
    int n0 = g * 4;
    int W, s, loc; level_of(n0, W, s, loc);
    const float* cls = (s == 8) ? cls0 : (s == 16) ? cls1 : cls2;
    int hw = W * W;
    int y = loc / W, x = loc - y * W;
    const float* cp = cls + (size_t)b * NCLS * hw + y * W + x;   // 16B aligned

    int c0 = ch * CPC;
    float4 v = *(const float4*)(cp + (size_t)c0 * hw);
    u64 k0 = packkc(sigm_np(v.x), c0);
    u64 k1 = packkc(sigm_np(v.y), c0);
    u64 k2 = packkc(sigm_np(v.z), c0);
    u64 k3 = packkc(sigm_np(v.w), c0);
#pragma unroll
    for (int cc = 1; cc < CPC; ++cc) {
        int c = c0 + cc;
        v = *(const float4*)(cp + (size_t)c * hw);
        u64 t;
        t = packkc(sigm_np(v.x), c); if (t > k0) k0 = t;
        t = packkc(sigm_np(v.y), c); if (t > k1) k1 = t;
        t = packkc(sigm_np(v.z), c); if (t > k2) k2 = t;
        t = packkc(sigm_np(v.w), c); if (t > k3) k3 = t;
    }
    u64* p = part + ((size_t)ch * NB + b) * NPRIOR + n0;
    p[0] = k0; p[1] = k1; p[2] = k2; p[3] = k3;
}

// ---- Kernel A2: reduce chunks + obj sigmoid + threshold + compaction ----
__global__ void __launch_bounds__(256) score2_k(
    const float* __restrict__ ob0, const float* __restrict__ ob1, const float* __restrict__ ob2,
    const u64* __restrict__ part,
    float* __restrict__ sc, int* __restrict__ labels,
    u64* __restrict__ keys, int* __restrict__ cnts)
{
#pragma clang fp contract(off)
    int b = blockIdx.y;
    int g = blockIdx.x * 256 + threadIdx.x;
    if (g >= NPRIOR / 4) return;                 // inactive lanes drop from ballots
    int n0 = g * 4;
    int W, s, loc; level_of(n0, W, s, loc);
    const float* ob = (s == 8) ? ob0 : (s == 16) ? ob1 : ob2;
    int hw = W * W;
    int y = loc / W, x = loc - y * W;

    u64 k0 = 0, k1 = 0, k2 = 0, k3 = 0;
#pragma unroll
    for (int ch = 0; ch < PCH; ++ch) {
        const u64* p = part + ((size_t)ch * NB + b) * NPRIOR + n0;
        u64 t0 = p[0], t1 = p[1], t2 = p[2], t3 = p[3];
        if (t0 > k0) k0 = t0;
        if (t1 > k1) k1 = t1;
        if (t2 > k2) k2 = t2;
        if (t3 > k3) k3 = t3;
    }
    float4 tM;
    tM.x = __uint_as_float((unsigned)(k0 >> 32));
    tM.y = __uint_as_float((unsigned)(k1 >> 32));
    tM.z = __uint_as_float((unsigned)(k2 >> 32));
    tM.w = __uint_as_float((unsigned)(k3 >> 32));
    int4 lab;
    lab.x = (int)(~(unsigned)(k0 & 0xffffffffull));
    lab.y = (int)(~(unsigned)(k1 & 0xffffffffull));
    lab.z = (int)(~(unsigned)(k2 & 0xffffffffull));
    lab.w = (int)(~(unsigned)(k3 & 0xffffffffull));

    float4 o = *(const float4*)(ob + (size_t)b * hw + y * W + x);
    float4 sv;
    sv.x = tM.x * sigm_np(o.x);
    sv.y = tM.y * sigm_np(o.y);
    sv.z = tM.z * sigm_np(o.z);
    sv.w = tM.w * sigm_np(o.w);
    float4 scv;
    scv.x = (sv.x >= 0.65f) ? sv.x : 0.0f;
    scv.y = (sv.y >= 0.65f) ? sv.y : 0.0f;
    scv.z = (sv.z >= 0.65f) ? sv.z : 0.0f;
    scv.w = (sv.w >= 0.65f) ? sv.w : 0.0f;
    *(float4*)(sc + (size_t)b * NPRIOR + n0) = scv;
    *(int4*)(labels + (size_t)b * NPRIOR + n0) = lab;

    // wave-aggregated compaction (order-free; ranking restores stable order)
    int lane = threadIdx.x & 63;
#pragma unroll
    for (int e = 0; e < 4; ++e) {
        float se = (e == 0) ? scv.x : (e == 1) ? scv.y : (e == 2) ? scv.z : scv.w;
        bool val = se > 0.0f;
        u64 mb = __ballot(val);
        if (mb) {                                    // wave-uniform branch
            int lead = (int)__builtin_ctzll(mb);
            int base = 0;
            if (lane == lead) base = atomicAdd(&cnts[b * CPAD], (int)__popcll(mb));
            base = __shfl(base, lead);
            if (val) {
                int myoff = (int)__popcll(mb & ((1ull << lane) - 1ull));
                keys[(size_t)b * CAP + base + myoff] =
                    ((u64)__float_as_uint(se) << 32) | (unsigned)(~(unsigned)(n0 + e));
            }
        }
    }
}

// ---- Kernel B1: 2D-tiled all-pairs partial rank (atomicAdd accumulate) ----
__global__ void __launch_bounds__(256) rank_part(
    const u64* __restrict__ keys, const int* __restrict__ cnts,
    int* __restrict__ rankbuf)
{
    int b = blockIdx.y, tid = threadIdx.x;
    int cn = min(cnts[b * CPAD], CAP);
    int nt = (cn + 255) >> 8;                    // tiles per dimension
    int ntt = nt * nt;
    const u64* keyimg = keys + (size_t)b * CAP;
    int lane = tid & 63;

    for (int t = blockIdx.x; t < ntt; t += gridDim.x) {
        int it = t / nt, jt = t - it * nt;
        int i = it * 256 + tid;
        u64 ki = (i < cn) ? keyimg[i] : ~0ull;   // sentinel: counts stay 0
        int rank = 0;
        int jbase = jt * 256;
        int jend = min(jbase + 256, cn);
        for (int jb = jbase; jb < jend; jb += 64) {
            int j = jb + lane;
            u64 kv = (j < cn) ? keyimg[j] : 0ull;   // coalesced, cache-hot
            unsigned lo = (unsigned)kv, hi = (unsigned)(kv >> 32);
            int lim = jend - jb;                     // uniform
#pragma unroll
            for (int l = 0; l < 64; ++l) {
                unsigned jlo = __builtin_amdgcn_readlane(lo, l);
                unsigned jhi = __builtin_amdgcn_readlane(hi, l);
                u64 kj = ((u64)jhi << 32) | jlo;
                rank += (l < lim && kj > ki) ? 1 : 0;
            }
        }
        if (i < cn && rank > 0) atomicAdd(&rankbuf[(size_t)b * CAP + i], rank);
    }
}

// ---- Kernel B2: scatter by rank + decode + housekeeping ----
__global__ void __launch_bounds__(256) scatter_k(
    const u64* __restrict__ keys, const int* __restrict__ cnts,
    const int* __restrict__ rankbuf,
    const float* __restrict__ sc, const int* __restrict__ labels,
    const float* __restrict__ bb0, const float* __restrict__ bb1, const float* __restrict__ bb2,
    float4* __restrict__ sel_box, float* __restrict__ sel_score,
    int* __restrict__ sel_label, int* __restrict__ maxbits, u64* __restrict__ vmask)
{
#pragma clang fp contract(off)
    __shared__ float redbuf[256];
    int b = blockIdx.y, chunk = blockIdx.x, tid = threadIdx.x;
    int cn = min(cnts[b * CPAD], CAP);
    int base = chunk * 256;
    if (chunk != 0 && base >= cn) return;   // housekeeping lives in chunk 0

    const u64* keyimg = keys + (size_t)b * CAP;
    const int* labb = labels + (size_t)b * NPRIOR;
    const float* scb = sc + (size_t)b * NPRIOR;

    int i = base + tid;
    float lmax = 0.0f;
    if (i < cn) {
        int rank = rankbuf[(size_t)b * CAP + i];
        if (rank < KTOP) {
            u64 ki = keyimg[i];
            unsigned n = ~(unsigned)(ki & 0xffffffffull);
            float s = __uint_as_float((unsigned)(ki >> 32));
            float4 bx = decode32(b, (int)n, bb0, bb1, bb2);
            sel_box[(size_t)b * 1024 + rank] = bx;
            sel_score[(size_t)b * 1024 + rank] = s;
            sel_label[(size_t)b * 1024 + rank] = labb[n];
            lmax = fmaxf(fmaxf(fabsf(bx.x), fabsf(bx.y)),
                         fmaxf(fabsf(bx.z), fabsf(bx.w)));
        }
    }

    if (chunk == 0) {
        // rare fill path: fewer than K valid -> lowest-index zero-score priors
        if (cn < KTOP && tid == 0) {
            float lm = 0.0f;
            int r = cn;
            for (int n = 0; n < NPRIOR && r < KTOP; ++n) {
                if (scb[n] == 0.0f) {
                    float4 bx = decode32(b, n, bb0, bb1, bb2);
                    sel_box[(size_t)b * 1024 + r] = bx;
                    sel_score[(size_t)b * 1024 + r] = 0.0f;
                    sel_label[(size_t)b * 1024 + r] = labb[n];
                    lm = fmaxf(lm, fmaxf(fmaxf(fabsf(bx.x), fabsf(bx.y)),
                                         fmaxf(fabsf(bx.z), fabsf(bx.w))));
                    ++r;
                }
            }
            lmax = fmaxf(lmax, lm);
        }
        if (tid < 24) {   // padding rows 1000..1023 (excluded via vmask)
            sel_box[(size_t)b * 1024 + 1000 + tid] = make_float4(0.f, 0.f, 0.f, 0.f);
            sel_score[(size_t)b * 1024 + 1000 + tid] = 0.0f;
            sel_label[(size_t)b * 1024 + 1000 + tid] = 0;
        }
        if (tid < 16) {   // vmask closed form
            int vc = min(cn, KTOP);
            int lo = tid * 64;
            u64 m;
            if (vc >= lo + 64)      m = ~0ull;
            else if (vc <= lo)      m = 0ull;
            else                    m = (1ull << (vc - lo)) - 1ull;
            vmask[b * 16 + tid] = m;
        }
    }

    redbuf[tid] = lmax;
    __syncthreads();
    for (int off = 128; off > 0; off >>= 1) {
        if (tid < off) redbuf[tid] = fmaxf(redbuf[tid], redbuf[tid + off]);
        __syncthreads();
    }
    if (tid == 0) atomicMax(&maxbits[b * CPAD], __float_as_int(redbuf[0]));
}

// ---- Kernel C: ballot-free suppression bitmask, per-lane column ownership ----
// Cmask[(b*16 + rg)*1024 + col] : bit j = "row rg*64+j suppresses col" (row<col).
// Only tiles rg <= cg are computed/written; nms reads only rg <= col-group.
// grid (64, NB): blockIdx.x = rgq*16 + cg; waves cover rg = rgq*4 + wave.
__global__ void __launch_bounds__(256) build_mask_T(
    const float4* __restrict__ sel_box, const int* __restrict__ sel_label,
    const int* __restrict__ maxbits, u64* __restrict__ Cmask)
{
#pragma clang fp contract(off)
    __shared__ float4 obr[256];   // offset row boxes for this rg-quad
    __shared__ float arr[256];    // their areas
    int b = blockIdx.y;
    int cg = blockIdx.x & 15, rgq = blockIdx.x >> 4;
    if (rgq * 4 > cg) return;                    // block-uniform triangle skip
    int tid = threadIdx.x, wave = tid >> 6, lane = tid & 63;
    float mc = __int_as_float(maxbits[b * CPAD]) + 1.0f;   // max_coord

    {   // stage rows [rgq*256, rgq*256+256) with class offset + area
        int row = rgq * 256 + tid;
        float4 v = sel_box[(size_t)b * 1024 + row];
        float off = (float)sel_label[(size_t)b * 1024 + row] * mc;
        v.x += off; v.y += off; v.z += off; v.w += off;
        obr[tid] = v;
        arr[tid] = (v.z - v.x) * (v.w - v.y);    // area of OFFSET box (as ref)
    }
    // per-lane column box (registers)
    int col = cg * 64 + lane;
    float4 a = sel_box[(size_t)b * 1024 + col];
    float offc = (float)sel_label[(size_t)b * 1024 + col] * mc;
    a.x += offc; a.y += offc; a.z += offc; a.w += offc;
    float ac = (a.z - a.x) * (a.w - a.y);
    __syncthreads();

    int rg = rgq * 4 + wave;
    if (rg > cg) return;                          // wave-uniform (after barrier)
    int rowbase = rg * 64;
    u64 bits = 0;
#pragma unroll 8
    for (int r = 0; r < 64; ++r) {
        int row = rowbase + r;
        float4 rb = obr[wave * 64 + r];           // broadcast LDS read
        float ra = arr[wave * 64 + r];
        bool pred = false;
        if (row < col && row < KTOP && col < KTOP) {
            float tlx = fmaxf(rb.x, a.x), tly = fmaxf(rb.y, a.y);   // row-first order
            float brx = fminf(rb.z, a.z), bry = fminf(rb.w, a.w);
            float w = fmaxf(brx - tlx, 0.0f), h = fmaxf(bry - tly, 0.0f);
            float inter = w * h;
            float uni = (ra + ac) - inter;        // row-area + col-area, as ref
            float iou = inter / (uni + 1e-6f);
            pred = iou > 0.65f;
        }
        bits |= pred ? (1ull << r) : 0ull;
    }
    Cmask[((size_t)b * 16 + rg) * 1024 + col] = bits;   // 512B coalesced/wave
}

// ---- Kernel D: ballot-fixpoint greedy NMS + output (coalesced Cmask reads) ----
__global__ void __launch_bounds__(64) nms_fixpoint_write(
    const u64* __restrict__ Cmask, const u64* __restrict__ vmask,
    const float4* __restrict__ sel_box, const float* __restrict__ sel_score,
    const int* __restrict__ sel_label, float* __restrict__ out)
{
    int b = blockIdx.x, lane = threadIdx.x;
    const u64* Cimg = Cmask + (size_t)b * 16 * 1024;
    u64 Khist[16];
#pragma unroll
    for (int g = 0; g < 16; ++g) {
        int col = g * 64 + lane;
        bool supp = false;
#pragma unroll
        for (int gp = 0; gp < g; ++gp)
            supp |= (Cimg[(size_t)gp * 1024 + col] & Khist[gp]) != 0ull;
        u64 V = vmask[b * 16 + g] & ~__ballot(supp);
        u64 T = Cimg[(size_t)g * 1024 + col];
        u64 K = V;
        for (int it = 0; it < 64; ++it) {
            u64 Knew = V & ~__ballot((T & K) != 0ull);
            if (Knew == K) break;        // wave-uniform branch
            K = Knew;
        }
        Khist[g] = K;
    }

    const size_t selo = (size_t)b * 1024;
    float* lab_o = out + (size_t)NB * KTOP * 5;
    float* keep_o = lab_o + (size_t)NB * KTOP;
#pragma unroll
    for (int g = 0; g < 16; ++g) {
        int k = g * 64 + lane;
        if (k >= KTOP) break;
        bool fin = (Khist[g] >> lane) & 1ull;
        float4 bx = sel_box[selo + k];
        float s = sel_score[selo + k];
        int lb = sel_label[selo + k];
        size_t o5 = ((size_t)b * KTOP + k) * 5;
        out[o5 + 0] = fin ? bx.x : 0.0f;
        out[o5 + 1] = fin ? bx.y : 0.0f;
        out[o5 + 2] = fin ? bx.z : 0.0f;
        out[o5 + 3] = fin ? bx.w : 0.0f;
        out[o5 + 4] = fin ? s : 0.0f;
        lab_o[b * KTOP + k] = fin ? (float)lb : -1.0f;
        keep_o[b * KTOP + k] = fin ? 1.0f : 0.0f;
    }
}

extern "C" void kernel_launch(void* const* d_in, const int* in_sizes, int n_in,
                              void* d_out, int out_size, void* d_ws, size_t ws_size,
                              hipStream_t stream) {
    const float* cls0 = (const float*)d_in[0];
    const float* cls1 = (const float*)d_in[1];
    const float* cls2 = (const float*)d_in[2];
    const float* bb0  = (const float*)d_in[3];
    const float* bb1  = (const float*)d_in[4];
    const float* bb2  = (const float*)d_in[5];
    const float* ob0  = (const float*)d_in[6];
    const float* ob1  = (const float*)d_in[7];
    const float* ob2  = (const float*)d_in[8];
    float* out = (float*)d_out;

    char* w = (char*)d_ws;
    size_t used = 0;
    auto alloc = [&](size_t bytes) -> void* {
        void* p = (void*)(w + used);
        used += (bytes + 255) & ~(size_t)255;
        return p;
    };
    float* sc        = (float*)alloc((size_t)NB * NPRIOR * 4);
    int* labels      = (int*)alloc((size_t)NB * NPRIOR * 4);
    u64* keys        = (u64*)alloc((size_t)NB * CAP * 8);
    u64* part        = (u64*)alloc((size_t)PCH * NB * NPRIOR * 8);
    int* zeroed      = (int*)alloc((size_t)(2 * NB * CPAD + NB * CAP) * 4); // cnts|maxbits|rankbuf
    float4* sel_box  = (float4*)alloc((size_t)NB * 1024 * 16);
    float* sel_score = (float*)alloc((size_t)NB * 1024 * 4);
    int* sel_label   = (int*)alloc((size_t)NB * 1024 * 4);
    u64* vmask       = (u64*)alloc((size_t)NB * 16 * 8);
    u64* Cmask       = (u64*)alloc((size_t)NB * 16 * 1024 * 8);

    if (used > ws_size) return;   // OOB-write guard

    int* cnts = zeroed;
    int* maxbits = zeroed + NB * CPAD;
    int* rankbuf = zeroed + 2 * NB * CPAD;
    hipMemsetAsync(zeroed, 0, (size_t)(2 * NB * CPAD + NB * CAP) * 4, stream);

    score1_k<<<dim3((NPRIOR / 4 + 255) / 256, PCH, NB), 256, 0, stream>>>(
        cls0, cls1, cls2, part);
    score2_k<<<dim3((NPRIOR / 4 + 255) / 256, NB), 256, 0, stream>>>(
        ob0, ob1, ob2, part, sc, labels, keys, cnts);
    rank_part<<<dim3(64, NB), 256, 0, stream>>>(keys, cnts, rankbuf);
    scatter_k<<<dim3((CAP + 255) / 256, NB), 256, 0, stream>>>(
        keys, cnts, rankbuf, sc, labels, bb0, bb1, bb2,
        sel_box, sel_score, sel_label, maxbits, vmask);
    build_mask_T<<<dim3(64, NB), 256, 0, stream>>>(sel_box, sel_label, maxbits, Cmask);
    nms_fixpoint_write<<<NB, 64, 0, stream>>>(
        Cmask, vmask, sel_box, sel_score, sel_label, out);
}